// Round 7
// baseline (24.180 us; speedup 1.0000x reference)
//
#include <hip/hip_runtime.h>

#define TPB  64
#define TILE 64
#define NT   4
#define IN_FLT  6528          // 64*102 floats of rotation data per tile
#define BUF_FLT 6720          // + 64*3 root floats; 26880 B per tile buffer

typedef const __attribute__((address_space(1))) void g_void;
typedef __attribute__((address_space(3))) void lds_void;

// Counted vmcnt wait. N must count ONLY the DMA (global_load_lds) ops issued
// after the batch we need completed — never stores: store retirement order vs
// loads is unverified, and pending stores only make the wait stricter, which
// is safe. DMA-vs-DMA in-order retirement is the m135/m218-verified property.
#define WAITV(n) do {                                           \
        asm volatile("s_waitcnt vmcnt(" #n ")" ::: "memory");   \
        __builtin_amdgcn_sched_barrier(0);                      \
    } while (0)

__device__ __forceinline__ void fence_lgkm() {
    asm volatile("s_waitcnt lgkmcnt(0)" ::: "memory");
    __builtin_amdgcn_wave_barrier();
}

struct M3 { float a[9]; };
struct V3 { float x, y, z; };

__device__ __forceinline__ M3 rot6d(const float* r) {
    float x0 = r[0], x1 = r[1], x2 = r[2];
    float y0 = r[3], y1 = r[4], y2 = r[5];
    float inx = rsqrtf(fmaxf(x0*x0 + x1*x1 + x2*x2, 1e-16f));
    x0 *= inx; x1 *= inx; x2 *= inx;
    float z0 = x1*y2 - x2*y1;
    float z1 = x2*y0 - x0*y2;
    float z2 = x0*y1 - x1*y0;
    float inz = rsqrtf(fmaxf(z0*z0 + z1*z1 + z2*z2, 1e-16f));
    z0 *= inz; z1 *= inz; z2 *= inz;
    float w0 = z1*x2 - z2*x1;
    float w1 = z2*x0 - z0*x2;
    float w2 = z0*x1 - z1*x0;
    M3 R;
    R.a[0] = x0; R.a[1] = w0; R.a[2] = z0;
    R.a[3] = x1; R.a[4] = w1; R.a[5] = z1;
    R.a[6] = x2; R.a[7] = w2; R.a[8] = z2;
    return R;
}

__device__ __forceinline__ M3 m3mul(const M3& A, const M3& B) {
    M3 C;
#pragma unroll
    for (int r = 0; r < 3; ++r)
#pragma unroll
        for (int c = 0; c < 3; ++c)
            C.a[3*r + c] = A.a[3*r + 0] * B.a[0 + c]
                         + A.a[3*r + 1] * B.a[3 + c]
                         + A.a[3*r + 2] * B.a[6 + c];
    return C;
}

__device__ __forceinline__ V3 step(const M3& P, V3 pp, int axis, float s) {
    V3 q;
    q.x = pp.x + s * P.a[0 + axis];
    q.y = pp.y + s * P.a[3 + axis];
    q.z = pp.z + s * P.a[6 + axis];
    return q;
}

// FK for one lane out of LDS; overlay results; coalesced store. 13 vmcnt stores.
template<bool FULL>
__device__ __forceinline__ void compute_store(float* buf, float* __restrict__ outp,
                                              const float* len, int t, int nv) {
    float res[51];
    const bool ok = FULL || (t < nv);
    if (ok) {
        const float* r6 = buf + t * 102;
        V3 q0; q0.x = buf[IN_FLT + t*3 + 0];
               q0.y = buf[IN_FLT + t*3 + 1];
               q0.z = buf[IN_FLT + t*3 + 2];
        M3 W0 = rot6d(r6 + 0);
        res[0] = q0.x; res[1] = q0.y; res[2] = q0.z;

        M3 W1 = m3mul(W0, rot6d(r6 + 1*6));  V3 q1 = step(W0, q0, 0, -len[0]);
        M3 W2 = m3mul(W1, rot6d(r6 + 2*6));  V3 q2 = step(W1, q1, 1, -len[1]);
        /* leaf 3 */                         V3 q3 = step(W2, q2, 1, -len[2]);
        res[3]=q1.x; res[4]=q1.y; res[5]=q1.z;
        res[6]=q2.x; res[7]=q2.y; res[8]=q2.z;
        res[9]=q3.x; res[10]=q3.y; res[11]=q3.z;

        M3 W4 = m3mul(W0, rot6d(r6 + 4*6));  V3 q4 = step(W0, q0, 0,  len[3]);
        M3 W5 = m3mul(W4, rot6d(r6 + 5*6));  V3 q5 = step(W4, q4, 1, -len[4]);
        /* leaf 6 */                         V3 q6 = step(W5, q5, 1, -len[5]);
        res[12]=q4.x; res[13]=q4.y; res[14]=q4.z;
        res[15]=q5.x; res[16]=q5.y; res[17]=q5.z;
        res[18]=q6.x; res[19]=q6.y; res[20]=q6.z;

        M3 W7 = m3mul(W0, rot6d(r6 + 7*6));  V3 q7 = step(W0, q0, 1,  len[6]);
        M3 W8 = m3mul(W7, rot6d(r6 + 8*6));  V3 q8 = step(W7, q7, 1,  len[7]);
        res[21]=q7.x; res[22]=q7.y; res[23]=q7.z;
        res[24]=q8.x; res[25]=q8.y; res[26]=q8.z;

        M3 W9 = m3mul(W8, rot6d(r6 + 9*6));  V3 q9 = step(W8, q8, 1,  len[8]);
        /* leaf 10 */                        V3 q10 = step(W9, q9, 1, len[9]);
        res[27]=q9.x; res[28]=q9.y; res[29]=q9.z;
        res[30]=q10.x; res[31]=q10.y; res[32]=q10.z;

        M3 W11 = m3mul(W8,  rot6d(r6 + 11*6)); V3 q11 = step(W8,  q8,  0, len[10]);
        M3 W12 = m3mul(W11, rot6d(r6 + 12*6)); V3 q12 = step(W11, q11, 0, len[11]);
        /* leaf 13 */                          V3 q13 = step(W12, q12, 0, len[12]);
        res[33]=q11.x; res[34]=q11.y; res[35]=q11.z;
        res[36]=q12.x; res[37]=q12.y; res[38]=q12.z;
        res[39]=q13.x; res[40]=q13.y; res[41]=q13.z;

        M3 W14 = m3mul(W8,  rot6d(r6 + 14*6)); V3 q14 = step(W8,  q8,  0, -len[13]);
        M3 W15 = m3mul(W14, rot6d(r6 + 15*6)); V3 q15 = step(W14, q14, 0, -len[14]);
        /* leaf 16 */                          V3 q16 = step(W15, q15, 0, -len[15]);
        res[42]=q14.x; res[43]=q14.y; res[44]=q14.z;
        res[45]=q15.x; res[46]=q15.y; res[47]=q15.z;
        res[48]=q16.x; res[49]=q16.y; res[50]=q16.z;
    }
    fence_lgkm();              // all input LDS reads retired before overlay write
    if (ok) {
        float* so = buf + t * 51;
#pragma unroll
        for (int m = 0; m < 51; ++m) so[m] = res[m];
    }
    fence_lgkm();
    if (FULL) {
        float4* o4 = (float4*)outp;
        const float4* l4 = (const float4*)buf;
#pragma unroll
        for (int r = 0; r < 12; ++r) o4[r * 64 + t] = l4[r * 64 + t];
        if (t < 48) o4[768 + t] = l4[768 + t];
    } else {
        const int nf = nv * 51;
        for (int e = t; e < nf; e += TPB) outp[e] = buf[e];
    }
    fence_lgkm();              // phase-4 ds_reads drained before buffer reuse
}

__global__ __launch_bounds__(TPB) void PoseDecoder_kernel(
    const float* __restrict__ rot,    // [BL,17,6]
    const float* __restrict__ bones,  // [B,16]
    const float* __restrict__ root,   // [BL,3]
    float* __restrict__ out,          // [BL,17,3]
    int BL, int L)
{
    __shared__ __align__(16) float s_buf[2][BUF_FLT];   // 53760 B
    const int t = threadIdx.x;
    const long long blk_base = (long long)blockIdx.x * (NT * TILE);

    // LDS destinations are direct expressions on s_buf (known LDS object) so
    // the generic->AS(3) cast folds without the aperture null-check that ICEs
    // the gfx950 backend. 30 DMA ops per STAGE: 25x16B + 2x4B rotation tail
    // + 3x4B root (only 4B/16B widths — both HW-verified).
#define STAGE(sbase, BUFI) do {                                                \
        const char* gb_ = (const char*)rot + (size_t)(sbase) * 408;            \
        _Pragma("unroll")                                                      \
        for (int r_ = 0; r_ < 25; ++r_)                                        \
            __builtin_amdgcn_global_load_lds(                                  \
                (g_void*)(gb_ + r_ * 1024 + t * 16),                           \
                (lds_void*)((char*)s_buf[BUFI] + r_ * 1024), 16, 0, 0);        \
        __builtin_amdgcn_global_load_lds((g_void*)(gb_ + 25600 + t * 4),       \
                (lds_void*)((char*)s_buf[BUFI] + 25600), 4, 0, 0);             \
        __builtin_amdgcn_global_load_lds((g_void*)(gb_ + 25856 + t * 4),       \
                (lds_void*)((char*)s_buf[BUFI] + 25856), 4, 0, 0);             \
        const char* gr_ = (const char*)root + (size_t)(sbase) * 12;            \
        _Pragma("unroll")                                                      \
        for (int r_ = 0; r_ < 3; ++r_)                                         \
            __builtin_amdgcn_global_load_lds(                                  \
                (g_void*)(gr_ + r_ * 256 + t * 4),                             \
                (lds_void*)((char*)(s_buf[BUFI] + IN_FLT) + r_ * 256), 4, 0, 0);\
    } while (0)

    const bool full_block = (blk_base + NT * TILE <= BL) &&
                            (blk_base / L == (blk_base + NT * TILE - 1) / L);

    if (full_block) {
        // one bone-set for the whole block -> SGPR lengths
        const float* bl = bones + (size_t)(blk_base / L) * 16;
        float len[16];
#pragma unroll
        for (int k = 0; k < 16; ++k) len[k] = bl[k];

        STAGE(blk_base + 0 * TILE, 0);   // DMA outstanding: 30
        STAGE(blk_base + 1 * TILE, 1);   // DMA outstanding: 60

        // need tile0 done; later DMA = dma1 (30). Stores not counted in N.
        WAITV(30);
        compute_store<true>(s_buf[0], out + (blk_base + 0*TILE) * 51, len, t, TILE);
        STAGE(blk_base + 2 * TILE, 0);

        // need tile1 done; later DMA = dma2 (30)
        WAITV(30);
        compute_store<true>(s_buf[1], out + (blk_base + 1*TILE) * 51, len, t, TILE);
        STAGE(blk_base + 3 * TILE, 1);

        // need tile2 done; later DMA = dma3 (30)
        WAITV(30);
        compute_store<true>(s_buf[0], out + (blk_base + 2*TILE) * 51, len, t, TILE);

        // need tile3 done; no later DMA -> full drain (also drains stores)
        WAITV(0);
        compute_store<true>(s_buf[1], out + (blk_base + 3*TILE) * 51, len, t, TILE);
    } else {
        // generic fallback (partial block or bone-boundary crossing): tile at a
        // time, scalar staging, full drains. Correct but slow; unused at BL=131072.
        for (int i = 0; i < NT; ++i) {
            long long sbase = blk_base + (long long)i * TILE;
            if (sbase >= BL) break;
            int nv = (int)((BL - sbase) < TILE ? (BL - sbase) : TILE);
            float* buf = s_buf[i & 1];
            for (int e = t; e < nv * 102; e += TPB)
                buf[e] = rot[sbase * 102 + e];
            for (int e = t; e < nv * 3; e += TPB)
                buf[IN_FLT + e] = root[sbase * 3 + e];
            float len[16];
            {
                long long gs = sbase + (t < nv ? t : 0);
                const float* bl = bones + (size_t)(gs / L) * 16;
#pragma unroll
                for (int k = 0; k < 16; ++k) len[k] = bl[k];
            }
            asm volatile("s_waitcnt vmcnt(0) lgkmcnt(0)" ::: "memory");
            __builtin_amdgcn_wave_barrier();
            compute_store<false>(buf, out + sbase * 51, len, t, nv);
        }
    }
#undef STAGE
}

extern "C" void kernel_launch(void* const* d_in, const int* in_sizes, int n_in,
                              void* d_out, int out_size, void* d_ws, size_t ws_size,
                              hipStream_t stream) {
    const float* rot   = (const float*)d_in[0];
    const float* bones = (const float*)d_in[1];
    const float* root  = (const float*)d_in[2];
    float* out = (float*)d_out;

    int BL = in_sizes[0] / 102;     // 17 joints * 6
    int B  = in_sizes[1] / 16;      // 16 bones
    int L  = BL / B;

    int grid = (BL + NT * TILE - 1) / (NT * TILE);
    PoseDecoder_kernel<<<grid, TPB, 0, stream>>>(rot, bones, root, out, BL, L);
}

// Round 8
// 20.758 us; speedup vs baseline: 1.1649x; 1.1649x over previous
//
#include <hip/hip_runtime.h>

#define TPB 64          // one wave per block — wave-synchronous, no barriers
#define NFLT 102        // staged floats per sample

typedef const __attribute__((address_space(1))) void g_void;
typedef __attribute__((address_space(3))) void lds_void;

struct M3 { float a[9]; };
struct V3 { float x, y, z; };

__device__ __forceinline__ void fence_lgkm() {
    asm volatile("s_waitcnt lgkmcnt(0)" ::: "memory");
    __builtin_amdgcn_wave_barrier();
}

// rotation from 6 floats held in three float2 registers (v[0..2])
__device__ __forceinline__ M3 rot6d2(const float2* v) {
    float x0 = v[0].x, x1 = v[0].y, x2 = v[1].x;
    float y0 = v[1].y, y1 = v[2].x, y2 = v[2].y;
    float inx = rsqrtf(fmaxf(x0*x0 + x1*x1 + x2*x2, 1e-16f));
    x0 *= inx; x1 *= inx; x2 *= inx;
    float z0 = x1*y2 - x2*y1;
    float z1 = x2*y0 - x0*y2;
    float z2 = x0*y1 - x1*y0;
    float inz = rsqrtf(fmaxf(z0*z0 + z1*z1 + z2*z2, 1e-16f));
    z0 *= inz; z1 *= inz; z2 *= inz;
    float w0 = z1*x2 - z2*x1;
    float w1 = z2*x0 - z0*x2;
    float w2 = z0*x1 - z1*x0;
    M3 R;
    R.a[0] = x0; R.a[1] = w0; R.a[2] = z0;
    R.a[3] = x1; R.a[4] = w1; R.a[5] = z1;
    R.a[6] = x2; R.a[7] = w2; R.a[8] = z2;
    return R;
}

__device__ __forceinline__ M3 m3mul(const M3& A, const M3& B) {
    M3 C;
#pragma unroll
    for (int r = 0; r < 3; ++r)
#pragma unroll
        for (int c = 0; c < 3; ++c)
            C.a[3*r + c] = A.a[3*r + 0] * B.a[0 + c]
                         + A.a[3*r + 1] * B.a[3 + c]
                         + A.a[3*r + 2] * B.a[6 + c];
    return C;
}

__device__ __forceinline__ V3 step(const M3& P, V3 pp, int axis, float s) {
    V3 q;
    q.x = pp.x + s * P.a[0 + axis];
    q.y = pp.y + s * P.a[3 + axis];
    q.z = pp.z + s * P.a[6 + axis];
    return q;
}

__device__ __forceinline__ void put(float* so, int j, V3 q) {
    so[3*j + 0] = q.x; so[3*j + 1] = q.y; so[3*j + 2] = q.z;
}

// FK from registers (v = 51 float2 of the lane's sample), writing each joint
// position straight to the LDS overlay at `so`.
__device__ __forceinline__ void fk_from_regs(const float2* v, float* so,
                                             const float* len,
                                             float rx, float ry, float rz) {
    V3 q0; q0.x = rx; q0.y = ry; q0.z = rz;
    so[0] = rx; so[1] = ry; so[2] = rz;
    M3 W0 = rot6d2(v + 0);

    // chain 0 -> 1 -> 2 -> 3
    M3 W1 = m3mul(W0, rot6d2(v + 3*1));  V3 q1 = step(W0, q0, 0, -len[0]);  put(so, 1, q1);
    M3 W2 = m3mul(W1, rot6d2(v + 3*2));  V3 q2 = step(W1, q1, 1, -len[1]);  put(so, 2, q2);
    /* leaf 3 */                         V3 q3 = step(W2, q2, 1, -len[2]);  put(so, 3, q3);

    // chain 0 -> 4 -> 5 -> 6
    M3 W4 = m3mul(W0, rot6d2(v + 3*4));  V3 q4 = step(W0, q0, 0,  len[3]);  put(so, 4, q4);
    M3 W5 = m3mul(W4, rot6d2(v + 3*5));  V3 q5 = step(W4, q4, 1, -len[4]);  put(so, 5, q5);
    /* leaf 6 */                         V3 q6 = step(W5, q5, 1, -len[5]);  put(so, 6, q6);

    // chain 0 -> 7 -> 8
    M3 W7 = m3mul(W0, rot6d2(v + 3*7));  V3 q7 = step(W0, q0, 1,  len[6]);  put(so, 7, q7);
    M3 W8 = m3mul(W7, rot6d2(v + 3*8));  V3 q8 = step(W7, q7, 1,  len[7]);  put(so, 8, q8);

    // chain 8 -> 9 -> 10
    M3 W9 = m3mul(W8, rot6d2(v + 3*9));  V3 q9 = step(W8, q8, 1,  len[8]);  put(so, 9, q9);
    /* leaf 10 */                        V3 q10 = step(W9, q9, 1, len[9]);  put(so, 10, q10);

    // chain 8 -> 11 -> 12 -> 13
    M3 W11 = m3mul(W8,  rot6d2(v + 3*11)); V3 q11 = step(W8,  q8,  0, len[10]); put(so, 11, q11);
    M3 W12 = m3mul(W11, rot6d2(v + 3*12)); V3 q12 = step(W11, q11, 0, len[11]); put(so, 12, q12);
    /* leaf 13 */                          V3 q13 = step(W12, q12, 0, len[12]); put(so, 13, q13);

    // chain 8 -> 14 -> 15 -> 16
    M3 W14 = m3mul(W8,  rot6d2(v + 3*14)); V3 q14 = step(W8,  q8,  0, -len[13]); put(so, 14, q14);
    M3 W15 = m3mul(W14, rot6d2(v + 3*15)); V3 q15 = step(W14, q14, 0, -len[14]); put(so, 15, q15);
    /* leaf 16 */                          V3 q16 = step(W15, q15, 0, -len[15]); put(so, 16, q16);
}

__global__ __launch_bounds__(TPB) void PoseDecoder_kernel(
    const float* __restrict__ rot,    // [BL,17,6]
    const float* __restrict__ bones,  // [B,16]
    const float* __restrict__ root,   // [BL,3]
    float* __restrict__ out,          // [BL,17,3]
    int BL, int L)
{
    __shared__ __align__(16) float s_buf[TPB * NFLT];   // 26112 B -> 6 blocks/CU
    const int t = threadIdx.x;
    const long long base = (long long)blockIdx.x * TPB;

    const bool full = (base + TPB <= BL) &&
                      (base / L == (base + TPB - 1) / L);

    if (full) {
        // ---- DMA global -> LDS: 27 ops, all in flight at once ----
        const char* gb = (const char*)rot + (size_t)base * 408;
#pragma unroll
        for (int r = 0; r < 25; ++r)
            __builtin_amdgcn_global_load_lds(
                (g_void*)(gb + r * 1024 + t * 16),
                (lds_void*)((char*)s_buf + r * 1024), 16, 0, 0);
        __builtin_amdgcn_global_load_lds((g_void*)(gb + 25600 + t * 4),
                (lds_void*)((char*)s_buf + 25600), 4, 0, 0);
        __builtin_amdgcn_global_load_lds((g_void*)(gb + 25856 + t * 4),
                (lds_void*)((char*)s_buf + 25856), 4, 0, 0);

        // root direct to VGPR + bones scalar — ride the same latency window
        const long long gs = base + t;
        float rx = root[gs*3 + 0], ry = root[gs*3 + 1], rz = root[gs*3 + 2];
        const float* bl = bones + (size_t)(base / L) * 16;
        float len[16];
#pragma unroll
        for (int k = 0; k < 16; ++k) len[k] = bl[k];

        asm volatile("s_waitcnt vmcnt(0) lgkmcnt(0)" ::: "memory");
        __builtin_amdgcn_wave_barrier();

        // ---- bulk LDS -> registers: 51 independent b64 reads, one latency ----
        float2 v[51];
        const float2* l2 = (const float2*)((const char*)s_buf + t * 408);
#pragma unroll
        for (int k = 0; k < 51; ++k) v[k] = l2[k];
        fence_lgkm();                       // all reads done before overlay writes

        // ---- FK from registers, results written straight to overlay ----
        fk_from_regs(v, s_buf + t * 51, len, rx, ry, rz);
        fence_lgkm();                       // overlay writes done before read-back

        // ---- coalesced LDS -> global (float4) ----
        float4* o4 = (float4*)(out + (size_t)base * 51);
        const float4* l4 = (const float4*)s_buf;
#pragma unroll
        for (int r = 0; r < 12; ++r) o4[r * 64 + t] = l4[r * 64 + t];
        if (t < 48) o4[768 + t] = l4[768 + t];
    } else {
        // generic fallback (partial block / bone-boundary crossing): scalar
        // staging, full drain. Unused at BL=131072, L=256.
        const int nv = (int)((BL - base) < TPB ? (BL - base) : TPB);
        for (int e = t; e < nv * NFLT; e += TPB)
            s_buf[e] = rot[(size_t)base * NFLT + e];
        const long long gs = base + (t < nv ? t : 0);
        float rx = root[gs*3 + 0], ry = root[gs*3 + 1], rz = root[gs*3 + 2];
        const float* bl = bones + (size_t)(gs / L) * 16;
        float len[16];
#pragma unroll
        for (int k = 0; k < 16; ++k) len[k] = bl[k];
        asm volatile("s_waitcnt vmcnt(0) lgkmcnt(0)" ::: "memory");
        __builtin_amdgcn_wave_barrier();

        float2 v[51];
        const float2* l2 = (const float2*)((const char*)s_buf + t * 408);
#pragma unroll
        for (int k = 0; k < 51; ++k) v[k] = (t < nv) ? l2[k] : make_float2(0.f, 0.f);
        fence_lgkm();
        if (t < nv) fk_from_regs(v, s_buf + t * 51, len, rx, ry, rz);
        fence_lgkm();
        for (int e = t; e < nv * 51; e += TPB)
            out[(size_t)base * 51 + e] = s_buf[e];
    }
}

extern "C" void kernel_launch(void* const* d_in, const int* in_sizes, int n_in,
                              void* d_out, int out_size, void* d_ws, size_t ws_size,
                              hipStream_t stream) {
    const float* rot   = (const float*)d_in[0];
    const float* bones = (const float*)d_in[1];
    const float* root  = (const float*)d_in[2];
    float* out = (float*)d_out;

    int BL = in_sizes[0] / 102;     // 17 joints * 6
    int B  = in_sizes[1] / 16;      // 16 bones
    int L  = BL / B;

    int grid = (BL + TPB - 1) / TPB;
    PoseDecoder_kernel<<<grid, TPB, 0, stream>>>(rot, bones, root, out, BL, L);
}

// Round 9
// 18.459 us; speedup vs baseline: 1.3099x; 1.1246x over previous
//
#include <hip/hip_runtime.h>

#define TPB 64          // one wave per block — wave-synchronous, no barriers

struct M3 { float a[9]; };
struct V3 { float x, y, z; };

__device__ __forceinline__ void fence_lgkm() {
    asm volatile("s_waitcnt lgkmcnt(0)" ::: "memory");
    __builtin_amdgcn_wave_barrier();
}

// rotation from 6 floats held in three float2 registers
__device__ __forceinline__ M3 rot6d2(const float2* v) {
    float x0 = v[0].x, x1 = v[0].y, x2 = v[1].x;
    float y0 = v[1].y, y1 = v[2].x, y2 = v[2].y;
    float inx = rsqrtf(fmaxf(x0*x0 + x1*x1 + x2*x2, 1e-16f));
    x0 *= inx; x1 *= inx; x2 *= inx;
    float z0 = x1*y2 - x2*y1;
    float z1 = x2*y0 - x0*y2;
    float z2 = x0*y1 - x1*y0;
    float inz = rsqrtf(fmaxf(z0*z0 + z1*z1 + z2*z2, 1e-16f));
    z0 *= inz; z1 *= inz; z2 *= inz;
    float w0 = z1*x2 - z2*x1;
    float w1 = z2*x0 - z0*x2;
    float w2 = z0*x1 - z1*x0;
    M3 R;
    R.a[0] = x0; R.a[1] = w0; R.a[2] = z0;
    R.a[3] = x1; R.a[4] = w1; R.a[5] = z1;
    R.a[6] = x2; R.a[7] = w2; R.a[8] = z2;
    return R;
}

__device__ __forceinline__ M3 m3mul(const M3& A, const M3& B) {
    M3 C;
#pragma unroll
    for (int r = 0; r < 3; ++r)
#pragma unroll
        for (int c = 0; c < 3; ++c)
            C.a[3*r + c] = A.a[3*r + 0] * B.a[0 + c]
                         + A.a[3*r + 1] * B.a[3 + c]
                         + A.a[3*r + 2] * B.a[6 + c];
    return C;
}

__device__ __forceinline__ V3 step(const M3& P, V3 pp, int axis, float s) {
    V3 q;
    q.x = pp.x + s * P.a[0 + axis];
    q.y = pp.y + s * P.a[3 + axis];
    q.z = pp.z + s * P.a[6 + axis];
    return q;
}

__device__ __forceinline__ void put(float* so, int j, V3 q) {
    so[3*j + 0] = q.x; so[3*j + 1] = q.y; so[3*j + 2] = q.z;
}

// FK from per-joint register float2 triples, results straight to LDS overlay.
// v[u] maps to joints {0,1,2,4,5,7,8,9,11,12,14,15}.
__device__ __forceinline__ void fk_from_regs(const float2 v[12][3], float* so,
                                             const float* len,
                                             float rx, float ry, float rz) {
    V3 q0; q0.x = rx; q0.y = ry; q0.z = rz;
    so[0] = rx; so[1] = ry; so[2] = rz;
    M3 W0 = rot6d2(v[0]);

    // chain 0 -> 1 -> 2 -> 3
    M3 W1 = m3mul(W0, rot6d2(v[1]));  V3 q1 = step(W0, q0, 0, -len[0]);  put(so, 1, q1);
    M3 W2 = m3mul(W1, rot6d2(v[2]));  V3 q2 = step(W1, q1, 1, -len[1]);  put(so, 2, q2);
    /* leaf 3 */                      V3 q3 = step(W2, q2, 1, -len[2]);  put(so, 3, q3);

    // chain 0 -> 4 -> 5 -> 6
    M3 W4 = m3mul(W0, rot6d2(v[3]));  V3 q4 = step(W0, q0, 0,  len[3]);  put(so, 4, q4);
    M3 W5 = m3mul(W4, rot6d2(v[4]));  V3 q5 = step(W4, q4, 1, -len[4]);  put(so, 5, q5);
    /* leaf 6 */                      V3 q6 = step(W5, q5, 1, -len[5]);  put(so, 6, q6);

    // chain 0 -> 7 -> 8
    M3 W7 = m3mul(W0, rot6d2(v[5]));  V3 q7 = step(W0, q0, 1,  len[6]);  put(so, 7, q7);
    M3 W8 = m3mul(W7, rot6d2(v[6]));  V3 q8 = step(W7, q7, 1,  len[7]);  put(so, 8, q8);

    // chain 8 -> 9 -> 10
    M3 W9 = m3mul(W8, rot6d2(v[7]));  V3 q9 = step(W8, q8, 1,  len[8]);  put(so, 9, q9);
    /* leaf 10 */                     V3 q10 = step(W9, q9, 1, len[9]);  put(so, 10, q10);

    // chain 8 -> 11 -> 12 -> 13
    M3 W11 = m3mul(W8,  rot6d2(v[8]));  V3 q11 = step(W8,  q8,  0, len[10]); put(so, 11, q11);
    M3 W12 = m3mul(W11, rot6d2(v[9]));  V3 q12 = step(W11, q11, 0, len[11]); put(so, 12, q12);
    /* leaf 13 */                       V3 q13 = step(W12, q12, 0, len[12]); put(so, 13, q13);

    // chain 8 -> 14 -> 15 -> 16
    M3 W14 = m3mul(W8,  rot6d2(v[10])); V3 q14 = step(W8,  q8,  0, -len[13]); put(so, 14, q14);
    M3 W15 = m3mul(W14, rot6d2(v[11])); V3 q15 = step(W14, q14, 0, -len[14]); put(so, 15, q15);
    /* leaf 16 */                       V3 q16 = step(W15, q15, 0, -len[15]); put(so, 16, q16);
}

__global__ __launch_bounds__(TPB) void PoseDecoder_kernel(
    const float* __restrict__ rot,    // [BL,17,6]
    const float* __restrict__ bones,  // [B,16]
    const float* __restrict__ root,   // [BL,3]
    float* __restrict__ out,          // [BL,17,3]
    int BL, int L)
{
    __shared__ __align__(16) float s_out[TPB * 51];   // 13056 B -> 12 blocks/CU
    const int t = threadIdx.x;
    const long long base = (long long)blockIdx.x * TPB;
    const long long gs = base + t;
    const bool ok = gs < BL;

    // joints whose rotations are actually consumed (leaves 3,6,10,13,16 dead)
    constexpr int UJ[12] = {0, 1, 2, 4, 5, 7, 8, 9, 11, 12, 14, 15};

    // ---- per-lane direct global -> register loads: 36 independent dwordx2,
    //      all in flight at once; compute consumes in load order so the
    //      compiler's counted vmcnt waits start FK before the tail lands ----
    float2 v[12][3];
    const float2* g2 = (const float2*)(rot + (size_t)(ok ? gs : 0) * 102);  // 8-aligned
#pragma unroll
    for (int u = 0; u < 12; ++u)
#pragma unroll
        for (int k = 0; k < 3; ++k)
            v[u][k] = g2[UJ[u] * 3 + k];

    const long long rbase = (ok ? gs : 0) * 3;
    float rx = root[rbase + 0], ry = root[rbase + 1], rz = root[rbase + 2];

    // bone lengths: block-uniform on the fast path -> scalar loads (SGPRs)
    float len[16];
    if (base / L == (base + TPB - 1) / L) {
        const float* bl = bones + (size_t)(base / L) * 16;
#pragma unroll
        for (int k = 0; k < 16; ++k) len[k] = bl[k];
    } else {
        const float* bl = bones + (size_t)((ok ? gs : 0) / L) * 16;
#pragma unroll
        for (int k = 0; k < 16; ++k) len[k] = bl[k];
    }

    // ---- FK from registers, results straight to LDS overlay ----
    if (ok) fk_from_regs(v, s_out + t * 51, len, rx, ry, rz);
    fence_lgkm();                       // overlay writes visible wave-wide

    // ---- coalesced LDS -> global store (float4) ----
    if (base + TPB <= BL) {
        float4* o4 = (float4*)(out + (size_t)base * 51);
        const float4* l4 = (const float4*)s_out;
#pragma unroll
        for (int r = 0; r < 12; ++r) o4[r * 64 + t] = l4[r * 64 + t];
        if (t < 48) o4[768 + t] = l4[768 + t];
    } else {
        const int nf = (int)(BL - base) * 51;
        for (int e = t; e < nf; e += TPB)
            out[(size_t)base * 51 + e] = s_out[e];
    }
}

extern "C" void kernel_launch(void* const* d_in, const int* in_sizes, int n_in,
                              void* d_out, int out_size, void* d_ws, size_t ws_size,
                              hipStream_t stream) {
    const float* rot   = (const float*)d_in[0];
    const float* bones = (const float*)d_in[1];
    const float* root  = (const float*)d_in[2];
    float* out = (float*)d_out;

    int BL = in_sizes[0] / 102;     // 17 joints * 6
    int B  = in_sizes[1] / 16;      // 16 bones
    int L  = BL / B;

    int grid = (BL + TPB - 1) / TPB;
    PoseDecoder_kernel<<<grid, TPB, 0, stream>>>(rot, bones, root, out, BL, L);
}